// Round 1
// baseline (11136.810 us; speedup 1.0000x reference)
//
#include <hip/hip_runtime.h>
#include <stdint.h>

// Persistent cooperative-style kernel: 256 blocks x 256 threads, custom grid
// barrier (8-slot arrival counters, agent-scope release/acquire).
// Main loop per step: [A] aw=h@Wah^T+ax  [B] softmax+ctx (VALU, encT bf16)
// [C] r=relu(ctx@Wcc^T+cx)  [D] gates MFMA (i,f,g,o in one wave) + cell.
// Projection (out/proj_common/proj_batched/log_softmax) deferred to parallel
// post-phases over all 127 steps (M=8128 GEMMs).

#define DEV static __device__ __forceinline__

typedef __attribute__((ext_vector_type(8))) short short8;
typedef __attribute__((ext_vector_type(4))) float f32x4;
typedef unsigned short u16;

#define NBLK 256
#define TPB  256
#define NWAVE 1024
#define TS 127

struct Args {
  const float* enc;     // [64][512][512]
  const float* obe;     // [64][100][256]
  const int*   tidx;    // [64][128]
  const float* common;  // [1000][256]
  const float* Wattn;   // [512][768]
  const float* battn;   // [512]
  const float* Wcomb;   // [512][768]
  const float* bcomb;   // [512]
  const float* Wih;     // [2048][512]
  const float* bih;
  const float* Whh;
  const float* bhh;
  const float* Wout;    // [256][512]
  const float* bout;
  float* out;           // [64][127][1100]
  unsigned* bar;
  u16 *ax, *cx;         // [127*64][512] bf16 (x-parts + bias folded)
  u16 *xbf;             // [127*64][256]
  u16 *encT;            // [64][d=512][l=512] bf16 (transposed)
  u16 *Wax, *Wah, *Wcx, *Wcc;
  u16 *Wg;              // [2048][1024] = [Wih | Whh]
  u16 *WoutB;           // [256][512]
  u16 *commB;           // [1008][256] (padded, zero rows >=1000)
  u16 *obeB;            // [64][112][256] (padded, zero rows >=100)
  float *bg;            // [2048] = bih+bhh
  float *aw;            // [64][512]
  float *cst;           // [64][512] c state f32
  u16 *rbf;             // [64][512]
  u16 *h0, *h1;         // [64][512] ping-pong h bf16
  u16 *ctxbf;           // [64][512]
  u16 *hh;              // [127*64][512] h history bf16
  u16 *outbf;           // [127*64][256]
};

DEV u16 f2bf(float f) { union { float f; unsigned u; } v; v.f = f;
  return (u16)((v.u + 0x7fffu + ((v.u >> 16) & 1u)) >> 16); }
DEV float bf2f(u16 s) { union { unsigned u; float f; } v; v.u = ((unsigned)s) << 16; return v.f; }
DEV float sigm(float x) { return 1.f / (1.f + __expf(-x)); }
DEV float tanhfast(float x) { float e = __expf(2.f * x); return (e - 1.f) / (e + 1.f); }

#define MFMA(a,b,c) __builtin_amdgcn_mfma_f32_16x16x32_bf16((a),(b),(c),0,0,0)

DEV void gbar(unsigned* cnt, unsigned ep) {
  __syncthreads();   // compiler drains vmcnt before s_barrier -> block writes are in L2
  if (threadIdx.x == 0)
    __hip_atomic_fetch_add(&cnt[blockIdx.x & 7u], 1u, __ATOMIC_RELEASE, __HIP_MEMORY_SCOPE_AGENT);
  if (threadIdx.x < 8) {
    unsigned tgt = ep * (NBLK / 8u);
    while (__hip_atomic_load(&cnt[threadIdx.x], __ATOMIC_RELAXED, __HIP_MEMORY_SCOPE_AGENT) < tgt)
      __builtin_amdgcn_s_sleep(2);
    __threadfence();  // acquire: invalidate L1/stale L2 before reading others' data
  }
  __syncthreads();
}

__global__ __launch_bounds__(TPB) void attn_rnn_kernel(Args A) {
  const int tid  = (int)threadIdx.x;
  const int lane = tid & 63;
  const int lwv  = tid >> 6;
  const int swv  = lwv * NBLK + (int)blockIdx.x;   // wave id spread across blocks
  const int gtid = (int)blockIdx.x * TPB + tid;
  const int NT   = NBLK * TPB;
  const int l15  = lane & 15;
  const int koff = (lane >> 4) * 8;
  const int row4 = (lane >> 4) * 4;
  __shared__ float lds_p[4 * 512];
  unsigned ep = 0;

  // ---------------- P0: conversions / transpose / gather / zero ----------------
  for (int i = gtid; i < 512 * 256; i += NT) { int l = i >> 8, k = i & 255; A.Wax[i] = f2bf(A.Wattn[l * 768 + k]); }
  for (int i = gtid; i < 512 * 512; i += NT) { int l = i >> 9, d = i & 511; A.Wah[i] = f2bf(A.Wattn[l * 768 + 256 + d]); }
  for (int i = gtid; i < 512 * 256; i += NT) { int l = i >> 8, k = i & 255; A.Wcx[i] = f2bf(A.Wcomb[l * 768 + k]); }
  for (int i = gtid; i < 512 * 512; i += NT) { int l = i >> 9, d = i & 511; A.Wcc[i] = f2bf(A.Wcomb[l * 768 + 256 + d]); }
  for (int i = gtid; i < 2048 * 1024; i += NT) { int n = i >> 10, k = i & 1023;
    A.Wg[i] = f2bf(k < 512 ? A.Wih[n * 512 + k] : A.Whh[n * 512 + (k - 512)]); }
  for (int i = gtid; i < 256 * 512; i += NT) A.WoutB[i] = f2bf(A.Wout[i]);
  for (int i = gtid; i < 1008 * 256; i += NT) { int v = i >> 8; A.commB[i] = (v < 1000) ? f2bf(A.common[i]) : (u16)0; }
  for (int i = gtid; i < 64 * 112 * 256; i += NT) { int b = i / (112 * 256); int r = i - b * (112 * 256);
    int v = r >> 8; int k = r & 255; A.obeB[i] = (v < 100) ? f2bf(A.obe[(b * 100 + v) * 256 + k]) : (u16)0; }
  for (int i = gtid; i < 2048; i += NT) A.bg[i] = A.bih[i] + A.bhh[i];
  for (int i = gtid; i < 64 * 512; i += NT) { A.cst[i] = 0.f; A.h0[i] = 0; A.h1[i] = 0; }
  // enc transpose -> encT[b][d][l] bf16 (coalesced reads, 16B scatter writes)
  for (int task = swv; task < 4096; task += NWAVE) {
    int b = task >> 6, l0 = (task & 63) * 8;
    for (int dc = 0; dc < 8; ++dc) {
      int d = dc * 64 + lane;
      short8 s;
      for (int j = 0; j < 8; ++j) s[j] = (short)f2bf(A.enc[((b * 512) + l0 + j) * 512 + d]);
      *(short8*)(A.encT + ((b * 512) + d) * 512 + l0) = s;
    }
  }
  // embedding gather -> xbf[(t*64+b)][256]
  for (int task = swv; task < TS * 64; task += NWAVE) {
    int t = task >> 6, b = task & 63;
    int idx = A.tidx[b * 128 + t];
    const float* src = (idx < 1000) ? (A.common + idx * 256) : (A.obe + (b * 100 + (idx - 1000)) * 256);
    for (int j = 0; j < 4; ++j) { int k = j * 64 + lane; A.xbf[(t * 64 + b) * 256 + k] = f2bf(src[k]); }
  }
  gbar(A.bar, ++ep);

  // ---------------- P1: ax = x@Wax^T + battn ; cx = x@Wcx^T + bcomb ----------------
  for (int task = swv; task < 2 * 508 * 32; task += NWAVE) {
    int which = (task >= 508 * 32) ? 1 : 0;
    int tk = task - which * (508 * 32);
    int mt = tk >> 5, nt = tk & 31;
    const u16* Wp = which ? A.Wcx : A.Wax;
    const u16* Ap = A.xbf + (mt * 16 + l15) * 256 + koff;
    const u16* Bp = Wp + (nt * 16 + l15) * 256 + koff;
    f32x4 acc = {0.f, 0.f, 0.f, 0.f};
    for (int k0 = 0; k0 < 256; k0 += 32)
      acc = MFMA(*(const short8*)(Ap + k0), *(const short8*)(Bp + k0), acc);
    const float* bias = which ? A.bcomb : A.battn;
    u16* dst = which ? A.cx : A.ax;
    for (int r = 0; r < 4; ++r) {
      int m = mt * 16 + row4 + r, n = nt * 16 + l15;
      dst[m * 512 + n] = f2bf(acc[r] + bias[n]);
    }
  }
  gbar(A.bar, ++ep);

  // ---------------- main recurrence ----------------
  for (int t = 0; t < TS; ++t) {
    const u16* hcur = (t & 1) ? A.h1 : A.h0;
    u16* hnxt = (t & 1) ? A.h0 : A.h1;

    // Phase A: aw = h @ Wah^T + ax[t]   (M=64,N=512,K=512)
    if (swv < 128) {
      int mt = swv >> 5, nt = swv & 31;
      const u16* Ap = hcur + (mt * 16 + l15) * 512 + koff;
      const u16* Bp = A.Wah + (nt * 16 + l15) * 512 + koff;
      f32x4 acc = {0.f, 0.f, 0.f, 0.f};
      for (int k0 = 0; k0 < 512; k0 += 32)
        acc = MFMA(*(const short8*)(Ap + k0), *(const short8*)(Bp + k0), acc);
      for (int r = 0; r < 4; ++r) {
        int m = mt * 16 + row4 + r, n = nt * 16 + l15;
        A.aw[m * 512 + n] = acc[r] + bf2f(A.ax[(t * 64 + m) * 512 + n]);
      }
    }
    gbar(A.bar, ++ep);

    // Phase B: per-wave redundant softmax of aw row + ctx over encT
    if (swv < 512) {
      int b = swv >> 3, dc = swv & 7;
      float v[8]; float mx = -1e30f;
      for (int j = 0; j < 8; ++j) { v[j] = A.aw[b * 512 + j * 64 + lane]; mx = fmaxf(mx, v[j]); }
      for (int off = 1; off < 64; off <<= 1) mx = fmaxf(mx, __shfl_xor(mx, off));
      float s = 0.f;
      for (int j = 0; j < 8; ++j) { v[j] = __expf(v[j] - mx); s += v[j]; }
      for (int off = 1; off < 64; off <<= 1) s += __shfl_xor(s, off);
      float inv = 1.f / s;
      for (int j = 0; j < 8; ++j) lds_p[lwv * 512 + j * 64 + lane] = v[j];
      int d = dc * 64 + lane;
      const u16* row = A.encT + ((b * 512) + d) * 512;
      const float4* pp = (const float4*)(lds_p + lwv * 512);
      float acc = 0.f;
      for (int l0 = 0; l0 < 512; l0 += 8) {
        short8 ev = *(const short8*)(row + l0);
        float4 pa = pp[l0 >> 2], pb = pp[(l0 >> 2) + 1];
        acc += pa.x * bf2f((u16)ev[0]) + pa.y * bf2f((u16)ev[1]) + pa.z * bf2f((u16)ev[2]) + pa.w * bf2f((u16)ev[3]);
        acc += pb.x * bf2f((u16)ev[4]) + pb.y * bf2f((u16)ev[5]) + pb.z * bf2f((u16)ev[6]) + pb.w * bf2f((u16)ev[7]);
      }
      A.ctxbf[b * 512 + d] = f2bf(acc * inv);
    }
    gbar(A.bar, ++ep);

    // Phase C: r = relu(ctx @ Wcc^T + cx[t])
    if (swv < 128) {
      int mt = swv >> 5, nt = swv & 31;
      const u16* Ap = A.ctxbf + (mt * 16 + l15) * 512 + koff;
      const u16* Bp = A.Wcc + (nt * 16 + l15) * 512 + koff;
      f32x4 acc = {0.f, 0.f, 0.f, 0.f};
      for (int k0 = 0; k0 < 512; k0 += 32)
        acc = MFMA(*(const short8*)(Ap + k0), *(const short8*)(Bp + k0), acc);
      for (int r = 0; r < 4; ++r) {
        int m = mt * 16 + row4 + r, n = nt * 16 + l15;
        A.rbf[m * 512 + n] = f2bf(fmaxf(acc[r] + bf2f(A.cx[(t * 64 + m) * 512 + n]), 0.f));
      }
    }
    gbar(A.bar, ++ep);

    // Phase D: gates = [r|h] @ Wg^T ; i,f,g,o tiles in one wave -> local cell update
    if (swv < 128) {
      int mt = swv >> 5, ut = swv & 31;
      int am = mt * 16 + l15, nr = ut * 16 + l15;
      f32x4 ai = {0.f,0.f,0.f,0.f}, af = ai, ag = ai, ao = ai;
      for (int k0 = 0; k0 < 1024; k0 += 32) {
        const u16* Ap = (k0 < 512) ? (A.rbf + am * 512 + k0) : (hcur + am * 512 + (k0 - 512));
        short8 a = *(const short8*)(Ap + koff);
        short8 b0 = *(const short8*)(A.Wg + (nr) * 1024 + k0 + koff);
        short8 b1 = *(const short8*)(A.Wg + (512 + nr) * 1024 + k0 + koff);
        short8 b2 = *(const short8*)(A.Wg + (1024 + nr) * 1024 + k0 + koff);
        short8 b3 = *(const short8*)(A.Wg + (1536 + nr) * 1024 + k0 + koff);
        ai = MFMA(a, b0, ai); af = MFMA(a, b1, af); ag = MFMA(a, b2, ag); ao = MFMA(a, b3, ao);
      }
      for (int r = 0; r < 4; ++r) {
        int m = mt * 16 + row4 + r, u = ut * 16 + l15;
        float gi = ai[r] + A.bg[u];
        float gf = af[r] + A.bg[512 + u];
        float gg = ag[r] + A.bg[1024 + u];
        float go = ao[r] + A.bg[1536 + u];
        float cn = sigm(gf) * A.cst[m * 512 + u] + sigm(gi) * tanhfast(gg);
        float hn = sigm(go) * tanhfast(cn);
        A.cst[m * 512 + u] = cn;
        u16 hb = f2bf(hn);
        hnxt[m * 512 + u] = hb;
        A.hh[(t * 64 + m) * 512 + u] = hb;
      }
    }
    gbar(A.bar, ++ep);
  }

  // ---------------- P2: out = hh @ Wout^T + bout   (M=8128) ----------------
  for (int task = swv; task < 508 * 16; task += NWAVE) {
    int mt = task >> 4, nt = task & 15;
    const u16* Ap = A.hh + (mt * 16 + l15) * 512 + koff;
    const u16* Bp = A.WoutB + (nt * 16 + l15) * 512 + koff;
    f32x4 acc = {0.f,0.f,0.f,0.f};
    for (int k0 = 0; k0 < 512; k0 += 32)
      acc = MFMA(*(const short8*)(Ap + k0), *(const short8*)(Bp + k0), acc);
    for (int r = 0; r < 4; ++r) {
      int m = mt * 16 + row4 + r, n = nt * 16 + l15;
      A.outbf[m * 256 + n] = f2bf(acc[r] + A.bout[n]);
    }
  }
  gbar(A.bar, ++ep);

  // ---------------- P3: proj_common + proj_batched -> d_out (pre log-softmax) ----
  for (int task = swv; task < 508 * 63; task += NWAVE) {
    int mt = task / 63, nt = task - mt * 63;
    const u16* Ap = A.outbf + (mt * 16 + l15) * 256 + koff;
    const u16* Bp = A.commB + (nt * 16 + l15) * 256 + koff;
    f32x4 acc = {0.f,0.f,0.f,0.f};
    for (int k0 = 0; k0 < 256; k0 += 32)
      acc = MFMA(*(const short8*)(Ap + k0), *(const short8*)(Bp + k0), acc);
    for (int r = 0; r < 4; ++r) {
      int m = mt * 16 + row4 + r, n = nt * 16 + l15;
      if (n < 1000) { int tt = m >> 6, b = m & 63; A.out[((b * 127) + tt) * 1100 + n] = acc[r]; }
    }
  }
  for (int task = swv; task < 64 * 56; task += NWAVE) {
    int b = task / 56, r2 = task - b * 56;
    int mt = r2 / 7, nt = r2 - mt * 7;
    int am = mt * 16 + l15;
    const u16* Bp = A.obeB + (b * 112 + nt * 16 + l15) * 256 + koff;
    f32x4 acc = {0.f,0.f,0.f,0.f};
    short8 z8 = {0,0,0,0,0,0,0,0};
    for (int k0 = 0; k0 < 256; k0 += 32) {
      short8 a = (am < 127) ? *(const short8*)(A.outbf + (am * 64 + b) * 256 + k0 + koff) : z8;
      short8 b8 = *(const short8*)(Bp + k0);
      acc = MFMA(a, b8, acc);
    }
    for (int r = 0; r < 4; ++r) {
      int tt = mt * 16 + row4 + r, v = nt * 16 + l15;
      if (tt < 127 && v < 100) A.out[((b * 127) + tt) * 1100 + 1000 + v] = acc[r];
    }
  }
  gbar(A.bar, ++ep);

  // ---------------- P4: log-softmax in place, wave per (t,b) row ----------------
  for (int task = swv; task < TS * 64; task += NWAVE) {
    int t = task >> 6, b = task & 63;
    float* ptr = A.out + ((b * 127) + t) * 1100;
    float v[18]; float mx = -1e30f;
    for (int j = 0; j < 18; ++j) { int i = j * 64 + lane; v[j] = (i < 1100) ? ptr[i] : -1e30f; mx = fmaxf(mx, v[j]); }
    for (int off = 1; off < 64; off <<= 1) mx = fmaxf(mx, __shfl_xor(mx, off));
    float s = 0.f;
    for (int j = 0; j < 18; ++j) { int i = j * 64 + lane; if (i < 1100) s += __expf(v[j] - mx); }
    for (int off = 1; off < 64; off <<= 1) s += __shfl_xor(s, off);
    float lz = mx + __logf(s);
    for (int j = 0; j < 18; ++j) { int i = j * 64 + lane; if (i < 1100) ptr[i] = v[j] - lz; }
  }
}

extern "C" void kernel_launch(void* const* d_in, const int* in_sizes, int n_in,
                              void* d_out, int out_size, void* d_ws, size_t ws_size,
                              hipStream_t stream) {
  (void)in_sizes; (void)n_in; (void)out_size; (void)ws_size;
  char* ws = (char*)d_ws;
  size_t off = 0;
  auto alloc = [&](size_t bytes) -> void* {
    void* p = (void*)(ws + off);
    off = (off + bytes + 255) & ~((size_t)255);
    return p;
  };
  Args A;
  A.enc    = (const float*)d_in[0];
  A.obe    = (const float*)d_in[2];
  A.tidx   = (const int*)d_in[4];
  A.common = (const float*)d_in[5];
  A.Wattn  = (const float*)d_in[6];
  A.battn  = (const float*)d_in[7];
  A.Wcomb  = (const float*)d_in[8];
  A.bcomb  = (const float*)d_in[9];
  A.Wih    = (const float*)d_in[10];
  A.bih    = (const float*)d_in[11];
  A.Whh    = (const float*)d_in[12];
  A.bhh    = (const float*)d_in[13];
  A.Wout   = (const float*)d_in[14];
  A.bout   = (const float*)d_in[15];
  A.out    = (float*)d_out;
  A.bar    = (unsigned*)alloc(256);
  A.ax     = (u16*)alloc((size_t)TS * 64 * 512 * 2);
  A.cx     = (u16*)alloc((size_t)TS * 64 * 512 * 2);
  A.xbf    = (u16*)alloc((size_t)TS * 64 * 256 * 2);
  A.encT   = (u16*)alloc((size_t)64 * 512 * 512 * 2);
  A.Wax    = (u16*)alloc((size_t)512 * 256 * 2);
  A.Wah    = (u16*)alloc((size_t)512 * 512 * 2);
  A.Wcx    = (u16*)alloc((size_t)512 * 256 * 2);
  A.Wcc    = (u16*)alloc((size_t)512 * 512 * 2);
  A.Wg     = (u16*)alloc((size_t)2048 * 1024 * 2);
  A.WoutB  = (u16*)alloc((size_t)256 * 512 * 2);
  A.commB  = (u16*)alloc((size_t)1008 * 256 * 2);
  A.obeB   = (u16*)alloc((size_t)64 * 112 * 256 * 2);
  A.bg     = (float*)alloc((size_t)2048 * 4);
  A.aw     = (float*)alloc((size_t)64 * 512 * 4);
  A.cst    = (float*)alloc((size_t)64 * 512 * 4);
  A.rbf    = (u16*)alloc((size_t)64 * 512 * 2);
  A.h0     = (u16*)alloc((size_t)64 * 512 * 2);
  A.h1     = (u16*)alloc((size_t)64 * 512 * 2);
  A.ctxbf  = (u16*)alloc((size_t)64 * 512 * 2);
  A.hh     = (u16*)alloc((size_t)TS * 64 * 512 * 2);
  A.outbf  = (u16*)alloc((size_t)TS * 64 * 256 * 2);
  hipMemsetAsync(A.bar, 0, 256, stream);
  hipLaunchKernelGGL(attn_rnn_kernel, dim3(NBLK), dim3(TPB), 0, stream, A);
}

// Round 3
// 9793.169 us; speedup vs baseline: 1.1372x; 1.1372x over previous
//
#include <hip/hip_runtime.h>
#include <stdint.h>

// Persistent kernel, 256 blocks x 512 threads. enc is LDS-resident:
// block (b,dq) holds enc[b][:, dq*128:+128] as bf16 [512][128] = 128KB LDS.
// Per step: [A] aw=h@Wah^T+ax AND gh=h@Whh^T (640 wave-tiles)
//           [B] per-block softmax(aw[b]) + ctx from LDS (all blocks busy)
//           [C] r=relu(ctx@Wcc^T+cx)  [D] gates=r@Wih^T+gh+bg, cell update.
// Output projection + log-softmax deferred to parallel post-phases.

#define DEV static __device__ __forceinline__

typedef __attribute__((ext_vector_type(8))) short short8;
typedef __attribute__((ext_vector_type(4))) float f32x4;
typedef unsigned short u16;

#define NBLK 256
#define TPB  512
#define NWAVE 2048
#define TS 127
#define SMEM_BYTES 137344

struct Args {
  const float* enc;     // [64][512][512]
  const float* obe;     // [64][100][256]
  const int*   tidx;    // [64][128]
  const float* common;  // [1000][256]
  const float* Wattn;   // [512][768]
  const float* battn;   // [512]
  const float* Wcomb;   // [512][768]
  const float* bcomb;   // [512]
  const float* Wih;     // [2048][512]
  const float* bih;
  const float* Whh;
  const float* bhh;
  const float* Wout;    // [256][512]
  const float* bout;
  float* out;           // [64][127][1100]
  unsigned* bar;
  u16 *ax, *cx;         // [127*64][512] bf16 (x-part + bias folded)
  u16 *xbf;             // [127*64][256]
  u16 *Wax, *Wah, *Wcx, *Wcc;
  u16 *Wg;              // [2048][1024] = [Wih | Whh]
  u16 *WoutB;           // [256][512]
  u16 *commB;           // [1008][256] (padded)
  u16 *obeB;            // [64][112][256] (padded)
  float *bg;            // [2048] = bih+bhh
  float *aw;            // [64][512]
  float *gh;            // [64][2048]  h@Whh^T partial
  float *cst;           // [64][512] c state f32
  u16 *rbf;             // [64][512]
  u16 *h0, *h1;         // [64][512] ping-pong h bf16
  u16 *ctxbf;           // [64][512]
  u16 *hh;              // [127*64][512] h history bf16
  u16 *outbf;           // [127*64][256]
};

DEV u16 f2bf(float f) { union { float f; unsigned u; } v; v.f = f;
  return (u16)((v.u + 0x7fffu + ((v.u >> 16) & 1u)) >> 16); }
DEV float bf2f(u16 s) { union { unsigned u; float f; } v; v.u = ((unsigned)s) << 16; return v.f; }
DEV float sigm(float x) { return 1.f / (1.f + __expf(-x)); }
DEV float tanhfast(float x) { float e = __expf(2.f * x); return (e - 1.f) / (e + 1.f); }

#define MFMA(a,b,c) __builtin_amdgcn_mfma_f32_16x16x32_bf16((a),(b),(c),0,0,0)

DEV void gbar(unsigned* cnt, unsigned ep) {
  __syncthreads();
  if (threadIdx.x == 0)
    __hip_atomic_fetch_add(&cnt[blockIdx.x & 7u], 1u, __ATOMIC_RELEASE, __HIP_MEMORY_SCOPE_AGENT);
  if (threadIdx.x < 8) {
    unsigned tgt = ep * (NBLK / 8u);
    while (__hip_atomic_load(&cnt[threadIdx.x], __ATOMIC_RELAXED, __HIP_MEMORY_SCOPE_AGENT) < tgt)
      __builtin_amdgcn_s_sleep(2);
    __threadfence();
  }
  __syncthreads();
}

__global__ __launch_bounds__(TPB) void attn_rnn_kernel(Args A) {
  const int tid  = (int)threadIdx.x;
  const int lane = tid & 63;
  const int lwv  = tid >> 6;
  const int swv  = lwv * NBLK + (int)blockIdx.x;
  const int gtid = (int)blockIdx.x * TPB + tid;
  const int NT   = NBLK * TPB;
  const int l15  = lane & 15;
  const int koff = (lane >> 4) * 8;
  const int row4 = (lane >> 4) * 4;
  const int myb  = (int)blockIdx.x >> 2;   // batch owned by this block
  const int mydq = (int)blockIdx.x & 3;    // d-quarter owned
  extern __shared__ char smem[];
  u16*   encL   = (u16*)smem;               // [512][128] bf16, 128KB
  float* pbuf   = (float*)(smem + 131072);  // [512]
  float* part   = pbuf + 512;               // [8][128]
  float* redbuf = part + 1024;              // [16]
  unsigned ep = 0;

  // ---------------- P0: conversions / LDS enc load / gather / zero ----------------
  for (int i = tid; i < 512 * 128; i += TPB) {
    int l = i >> 7, dd = i & 127;
    encL[i] = f2bf(A.enc[((myb * 512) + l) * 512 + mydq * 128 + dd]);
  }
  for (int i = gtid; i < 512 * 256; i += NT) { int l = i >> 8, k = i & 255; A.Wax[i] = f2bf(A.Wattn[l * 768 + k]); }
  for (int i = gtid; i < 512 * 512; i += NT) { int l = i >> 9, d = i & 511; A.Wah[i] = f2bf(A.Wattn[l * 768 + 256 + d]); }
  for (int i = gtid; i < 512 * 256; i += NT) { int l = i >> 8, k = i & 255; A.Wcx[i] = f2bf(A.Wcomb[l * 768 + k]); }
  for (int i = gtid; i < 512 * 512; i += NT) { int l = i >> 9, d = i & 511; A.Wcc[i] = f2bf(A.Wcomb[l * 768 + 256 + d]); }
  for (int i = gtid; i < 2048 * 1024; i += NT) { int n = i >> 10, k = i & 1023;
    A.Wg[i] = f2bf(k < 512 ? A.Wih[n * 512 + k] : A.Whh[n * 512 + (k - 512)]); }
  for (int i = gtid; i < 256 * 512; i += NT) A.WoutB[i] = f2bf(A.Wout[i]);
  for (int i = gtid; i < 1008 * 256; i += NT) { int v = i >> 8; A.commB[i] = (v < 1000) ? f2bf(A.common[i]) : (u16)0; }
  for (int i = gtid; i < 64 * 112 * 256; i += NT) { int b = i / (112 * 256); int r = i - b * (112 * 256);
    int v = r >> 8; int k = r & 255; A.obeB[i] = (v < 100) ? f2bf(A.obe[(b * 100 + v) * 256 + k]) : (u16)0; }
  for (int i = gtid; i < 2048; i += NT) A.bg[i] = A.bih[i] + A.bhh[i];
  for (int i = gtid; i < 64 * 512; i += NT) { A.cst[i] = 0.f; A.h0[i] = 0; A.h1[i] = 0; }
  // embedding gather -> xbf[(t*64+b)][256]
  for (int task = swv; task < TS * 64; task += NWAVE) {
    int t = task >> 6, b = task & 63;
    int idx = A.tidx[b * 128 + t];
    const float* src = (idx < 1000) ? (A.common + idx * 256) : (A.obe + (b * 100 + (idx - 1000)) * 256);
    for (int j = 0; j < 4; ++j) { int k = j * 64 + lane; A.xbf[(t * 64 + b) * 256 + k] = f2bf(src[k]); }
  }
  gbar(A.bar, ++ep);

  // ---------------- P1: ax = x@Wax^T + battn ; cx = x@Wcx^T + bcomb ----------------
  for (int task = swv; task < 2 * 508 * 32; task += NWAVE) {
    int which = (task >= 508 * 32) ? 1 : 0;
    int tk = task - which * (508 * 32);
    int mt = tk >> 5, nt = tk & 31;
    const u16* Wp = which ? A.Wcx : A.Wax;
    const u16* Ap = A.xbf + (mt * 16 + l15) * 256 + koff;
    const u16* Bp = Wp + (nt * 16 + l15) * 256 + koff;
    f32x4 acc = {0.f, 0.f, 0.f, 0.f};
    for (int k0 = 0; k0 < 256; k0 += 32)
      acc = MFMA(*(const short8*)(Ap + k0), *(const short8*)(Bp + k0), acc);
    const float* bias = which ? A.bcomb : A.battn;
    u16* dst = which ? A.cx : A.ax;
    for (int r = 0; r < 4; ++r) {
      int m = mt * 16 + row4 + r, n = nt * 16 + l15;
      dst[m * 512 + n] = f2bf(acc[r] + bias[n]);
    }
  }
  gbar(A.bar, ++ep);

  // ---------------- main recurrence ----------------
  for (int t = 0; t < TS; ++t) {
    const u16* hcur = (t & 1) ? A.h1 : A.h0;
    u16* hnxt = (t & 1) ? A.h0 : A.h1;

    // Phase A: aw = h@Wah^T + ax[t] (128 tiles) AND gh = h@Whh^T (512 tiles)
    if (swv < 640) {
      if (swv < 128) {
        int mt = swv >> 5, nt = swv & 31;
        const u16* Ap = hcur + (mt * 16 + l15) * 512 + koff;
        const u16* Bp = A.Wah + (nt * 16 + l15) * 512 + koff;
        f32x4 acc = {0.f, 0.f, 0.f, 0.f};
        for (int k0 = 0; k0 < 512; k0 += 32)
          acc = MFMA(*(const short8*)(Ap + k0), *(const short8*)(Bp + k0), acc);
        for (int r = 0; r < 4; ++r) {
          int m = mt * 16 + row4 + r, n = nt * 16 + l15;
          A.aw[m * 512 + n] = acc[r] + bf2f(A.ax[(t * 64 + m) * 512 + n]);
        }
      } else {
        int t2 = swv - 128;
        int g = t2 >> 7, rem = t2 & 127;
        int mt = rem >> 5, nt = rem & 31;
        const u16* Ap = hcur + (mt * 16 + l15) * 512 + koff;
        const u16* Bp = A.Wg + (g * 512 + nt * 16 + l15) * 1024 + 512 + koff;
        f32x4 acc = {0.f, 0.f, 0.f, 0.f};
        for (int k0 = 0; k0 < 512; k0 += 32)
          acc = MFMA(*(const short8*)(Ap + k0), *(const short8*)(Bp + k0), acc);
        for (int r = 0; r < 4; ++r) {
          int m = mt * 16 + row4 + r, u = g * 512 + nt * 16 + l15;
          A.gh[m * 2048 + u] = acc[r];
        }
      }
    }
    gbar(A.bar, ++ep);

    // Phase B: per-block softmax(aw[myb]) + ctx from LDS enc slice
    {
      float a0 = A.aw[myb * 512 + tid];
      float mx = a0;
      for (int off = 1; off < 64; off <<= 1) mx = fmaxf(mx, __shfl_xor(mx, off));
      if (lane == 0) redbuf[lwv] = mx;
      __syncthreads();
      mx = redbuf[0];
      for (int k = 1; k < 8; ++k) mx = fmaxf(mx, redbuf[k]);
      float e = __expf(a0 - mx);
      pbuf[tid] = e;
      float s = e;
      for (int off = 1; off < 64; off <<= 1) s += __shfl_xor(s, off);
      if (lane == 0) redbuf[8 + lwv] = s;
      __syncthreads();
      s = 0.f;
      for (int k = 0; k < 8; ++k) s += redbuf[8 + k];
      float inv = 1.f / s;
      int dd2 = tid & 63, lh = tid >> 6;
      float c0 = 0.f, c1 = 0.f;
      const u16* eb = encL + dd2 * 2;
      const float* pb = pbuf + lh * 64;
      for (int j = 0; j < 64; ++j) {
        unsigned ev = *(const unsigned*)(eb + (lh * 64 + j) * 128);
        float p = pb[j];
        c0 += p * bf2f((u16)(ev & 0xffffu));
        c1 += p * bf2f((u16)(ev >> 16));
      }
      *(float2*)(part + lh * 128 + dd2 * 2) = make_float2(c0, c1);
      __syncthreads();
      if (tid < 128) {
        float cs = 0.f;
        for (int k = 0; k < 8; ++k) cs += part[k * 128 + tid];
        A.ctxbf[myb * 512 + mydq * 128 + tid] = f2bf(cs * inv);
      }
    }
    gbar(A.bar, ++ep);

    // Phase C: r = relu(ctx @ Wcc^T + cx[t])
    if (swv < 128) {
      int mt = swv >> 5, nt = swv & 31;
      const u16* Ap = A.ctxbf + (mt * 16 + l15) * 512 + koff;
      const u16* Bp = A.Wcc + (nt * 16 + l15) * 512 + koff;
      f32x4 acc = {0.f, 0.f, 0.f, 0.f};
      for (int k0 = 0; k0 < 512; k0 += 32)
        acc = MFMA(*(const short8*)(Ap + k0), *(const short8*)(Bp + k0), acc);
      for (int r = 0; r < 4; ++r) {
        int m = mt * 16 + row4 + r, n = nt * 16 + l15;
        A.rbf[m * 512 + n] = f2bf(fmaxf(acc[r] + bf2f(A.cx[(t * 64 + m) * 512 + n]), 0.f));
      }
    }
    gbar(A.bar, ++ep);

    // Phase D: gates = r@Wih^T + gh + bg ; cell update (4 gate tiles per wave)
    if (swv < 128) {
      int mt = swv >> 5, ut = swv & 31;
      int am = mt * 16 + l15, nr = ut * 16 + l15;
      f32x4 ai = {0.f,0.f,0.f,0.f}, af = ai, ag = ai, ao = ai;
      for (int k0 = 0; k0 < 512; k0 += 32) {
        short8 a = *(const short8*)(A.rbf + am * 512 + k0 + koff);
        short8 b0 = *(const short8*)(A.Wg + (nr) * 1024 + k0 + koff);
        short8 b1 = *(const short8*)(A.Wg + (512 + nr) * 1024 + k0 + koff);
        short8 b2 = *(const short8*)(A.Wg + (1024 + nr) * 1024 + k0 + koff);
        short8 b3 = *(const short8*)(A.Wg + (1536 + nr) * 1024 + k0 + koff);
        ai = MFMA(a, b0, ai); af = MFMA(a, b1, af); ag = MFMA(a, b2, ag); ao = MFMA(a, b3, ao);
      }
      for (int r = 0; r < 4; ++r) {
        int m = mt * 16 + row4 + r, u = ut * 16 + l15;
        const float* ghr = A.gh + m * 2048;
        float gi = ai[r] + ghr[u] + A.bg[u];
        float gf = af[r] + ghr[512 + u] + A.bg[512 + u];
        float gg = ag[r] + ghr[1024 + u] + A.bg[1024 + u];
        float go = ao[r] + ghr[1536 + u] + A.bg[1536 + u];
        float cn = sigm(gf) * A.cst[m * 512 + u] + sigm(gi) * tanhfast(gg);
        float hn = sigm(go) * tanhfast(cn);
        A.cst[m * 512 + u] = cn;
        u16 hb = f2bf(hn);
        hnxt[m * 512 + u] = hb;
        A.hh[(t * 64 + m) * 512 + u] = hb;
      }
    }
    gbar(A.bar, ++ep);
  }

  // ---------------- P2: out = hh @ Wout^T + bout   (M=8128) ----------------
  for (int task = swv; task < 508 * 16; task += NWAVE) {
    int mt = task >> 4, nt = task & 15;
    const u16* Ap = A.hh + (mt * 16 + l15) * 512 + koff;
    const u16* Bp = A.WoutB + (nt * 16 + l15) * 512 + koff;
    f32x4 acc = {0.f,0.f,0.f,0.f};
    for (int k0 = 0; k0 < 512; k0 += 32)
      acc = MFMA(*(const short8*)(Ap + k0), *(const short8*)(Bp + k0), acc);
    for (int r = 0; r < 4; ++r) {
      int m = mt * 16 + row4 + r, n = nt * 16 + l15;
      A.outbf[m * 256 + n] = f2bf(acc[r] + A.bout[n]);
    }
  }
  gbar(A.bar, ++ep);

  // ---------------- P3: proj_common + proj_batched -> d_out ----------------
  for (int task = swv; task < 508 * 63; task += NWAVE) {
    int mt = task / 63, nt = task - mt * 63;
    const u16* Ap = A.outbf + (mt * 16 + l15) * 256 + koff;
    const u16* Bp = A.commB + (nt * 16 + l15) * 256 + koff;
    f32x4 acc = {0.f,0.f,0.f,0.f};
    for (int k0 = 0; k0 < 256; k0 += 32)
      acc = MFMA(*(const short8*)(Ap + k0), *(const short8*)(Bp + k0), acc);
    for (int r = 0; r < 4; ++r) {
      int m = mt * 16 + row4 + r, n = nt * 16 + l15;
      if (n < 1000) { int tt = m >> 6, b = m & 63; A.out[((b * 127) + tt) * 1100 + n] = acc[r]; }
    }
  }
  for (int task = swv; task < 64 * 56; task += NWAVE) {
    int b = task / 56, r2 = task - b * 56;
    int mt = r2 / 7, nt = r2 - mt * 7;
    int am = mt * 16 + l15;
    const u16* Bp = A.obeB + (b * 112 + nt * 16 + l15) * 256 + koff;
    f32x4 acc = {0.f,0.f,0.f,0.f};
    short8 z8 = {0,0,0,0,0,0,0,0};
    for (int k0 = 0; k0 < 256; k0 += 32) {
      short8 a = (am < 127) ? *(const short8*)(A.outbf + (am * 64 + b) * 256 + k0 + koff) : z8;
      short8 b8 = *(const short8*)(Bp + k0);
      acc = MFMA(a, b8, acc);
    }
    for (int r = 0; r < 4; ++r) {
      int tt = mt * 16 + row4 + r, v = nt * 16 + l15;
      if (tt < 127 && v < 100) A.out[((b * 127) + tt) * 1100 + 1000 + v] = acc[r];
    }
  }
  gbar(A.bar, ++ep);

  // ---------------- P4: log-softmax in place, wave per (t,b) row ----------------
  for (int task = swv; task < TS * 64; task += NWAVE) {
    int t = task >> 6, b = task & 63;
    float* ptr = A.out + ((b * 127) + t) * 1100;
    float v[18]; float mx = -1e30f;
    for (int j = 0; j < 18; ++j) { int i = j * 64 + lane; v[j] = (i < 1100) ? ptr[i] : -1e30f; mx = fmaxf(mx, v[j]); }
    for (int off = 1; off < 64; off <<= 1) mx = fmaxf(mx, __shfl_xor(mx, off));
    float s = 0.f;
    for (int j = 0; j < 18; ++j) { int i = j * 64 + lane; if (i < 1100) s += __expf(v[j] - mx); }
    for (int off = 1; off < 64; off <<= 1) s += __shfl_xor(s, off);
    float lz = mx + __logf(s);
    for (int j = 0; j < 18; ++j) { int i = j * 64 + lane; if (i < 1100) ptr[i] = v[j] - lz; }
  }
}

extern "C" void kernel_launch(void* const* d_in, const int* in_sizes, int n_in,
                              void* d_out, int out_size, void* d_ws, size_t ws_size,
                              hipStream_t stream) {
  (void)in_sizes; (void)n_in; (void)out_size; (void)ws_size;
  char* ws = (char*)d_ws;
  size_t off = 0;
  auto alloc = [&](size_t bytes) -> void* {
    void* p = (void*)(ws + off);
    off = (off + bytes + 255) & ~((size_t)255);
    return p;
  };
  Args A;
  A.enc    = (const float*)d_in[0];
  A.obe    = (const float*)d_in[2];
  A.tidx   = (const int*)d_in[4];
  A.common = (const float*)d_in[5];
  A.Wattn  = (const float*)d_in[6];
  A.battn  = (const float*)d_in[7];
  A.Wcomb  = (const float*)d_in[8];
  A.bcomb  = (const float*)d_in[9];
  A.Wih    = (const float*)d_in[10];
  A.bih    = (const float*)d_in[11];
  A.Whh    = (const float*)d_in[12];
  A.bhh    = (const float*)d_in[13];
  A.Wout   = (const float*)d_in[14];
  A.bout   = (const float*)d_in[15];
  A.out    = (float*)d_out;
  A.bar    = (unsigned*)alloc(256);
  A.ax     = (u16*)alloc((size_t)TS * 64 * 512 * 2);
  A.cx     = (u16*)alloc((size_t)TS * 64 * 512 * 2);
  A.xbf    = (u16*)alloc((size_t)TS * 64 * 256 * 2);
  A.Wax    = (u16*)alloc((size_t)512 * 256 * 2);
  A.Wah    = (u16*)alloc((size_t)512 * 512 * 2);
  A.Wcx    = (u16*)alloc((size_t)512 * 256 * 2);
  A.Wcc    = (u16*)alloc((size_t)512 * 512 * 2);
  A.Wg     = (u16*)alloc((size_t)2048 * 1024 * 2);
  A.WoutB  = (u16*)alloc((size_t)256 * 512 * 2);
  A.commB  = (u16*)alloc((size_t)1008 * 256 * 2);
  A.obeB   = (u16*)alloc((size_t)64 * 112 * 256 * 2);
  A.bg     = (float*)alloc((size_t)2048 * 4);
  A.aw     = (float*)alloc((size_t)64 * 512 * 4);
  A.gh     = (float*)alloc((size_t)64 * 2048 * 4);
  A.cst    = (float*)alloc((size_t)64 * 512 * 4);
  A.rbf    = (u16*)alloc((size_t)64 * 512 * 2);
  A.h0     = (u16*)alloc((size_t)64 * 512 * 2);
  A.h1     = (u16*)alloc((size_t)64 * 512 * 2);
  A.ctxbf  = (u16*)alloc((size_t)64 * 512 * 2);
  A.hh     = (u16*)alloc((size_t)TS * 64 * 512 * 2);
  A.outbf  = (u16*)alloc((size_t)TS * 64 * 256 * 2);
  hipFuncSetAttribute((const void*)attn_rnn_kernel,
                      hipFuncAttributeMaxDynamicSharedMemorySize, SMEM_BYTES);
  hipMemsetAsync(A.bar, 0, 256, stream);
  hipLaunchKernelGGL(attn_rnn_kernel, dim3(NBLK), dim3(TPB), SMEM_BYTES, stream, A);
}

// Round 5
// 5381.625 us; speedup vs baseline: 2.0694x; 1.8197x over previous
//
#include <hip/hip_runtime.h>
#include <stdint.h>

// Persistent kernel, 256 blocks x 512 threads, enc LDS-resident (128KB/block).
// R4: relaxed-coherence mailbox protocol. Cross-block data (h, aw, gh, ctx,
// rbf) moves exclusively via sc0 sc1 (L1+L2-bypass) loads/stores to the
// device-coherent point. Grid barrier is pure relaxed atomics: NO release
// fence / threadfence => no per-barrier L2 writeback+invalidate => weights
// stay L2-hot across all 127 steps. Write-once data (converted weights, ax,
// cx, xbf, hh, outbf, inits) is sc01-stored once, normal-loaded afterward.

#define DEV static __device__ __forceinline__

typedef __attribute__((ext_vector_type(8))) short short8;
typedef __attribute__((ext_vector_type(4))) float f32x4;
typedef unsigned short u16;

#define NBLK 256
#define TPB  512
#define NWAVE 2048
#define TS 127
#define SMEM_BYTES 137344

struct Args {
  const float* enc;     // [64][512][512]
  const float* obe;     // [64][100][256]
  const int*   tidx;    // [64][128]
  const float* common;  // [1000][256]
  const float* Wattn;   // [512][768]
  const float* battn;   // [512]
  const float* Wcomb;   // [512][768]
  const float* bcomb;   // [512]
  const float* Wih;     // [2048][512]
  const float* bih;
  const float* Whh;
  const float* bhh;
  const float* Wout;    // [256][512]
  const float* bout;
  float* out;           // [64][127][1100]
  unsigned* bar;
  u16 *ax, *cx;         // [127*64][512] bf16 (x-part + bias folded)
  u16 *xbf;             // [127*64][256]
  u16 *Wax, *Wah, *Wcx, *Wcc;
  u16 *Wg;              // [2048][1024] = [Wih | Whh]
  u16 *WoutB;           // [256][512]
  u16 *commB;           // [1008][256] (padded)
  u16 *obeB;            // [64][112][256] (padded)
  float *bg;            // [2048] = bih+bhh
  float *aw;            // [64][512]
  float *gh;            // [64][512][4]  h@Whh^T, interleaved [m][ucol][gate]
  float *cst;           // [64][512] c state f32 (block-local access only)
  u16 *rbf;             // [64][512]
  u16 *h0, *h1;         // [64][512] ping-pong h bf16
  u16 *ctxbf;           // [64][512]
  u16 *hh;              // [127*64][512] h history bf16
  u16 *outbf;           // [127*64][256]
};

DEV u16 f2bf(float f) { union { float f; unsigned u; } v; v.f = f;
  return (u16)((v.u + 0x7fffu + ((v.u >> 16) & 1u)) >> 16); }
DEV float bf2f(u16 s) { union { unsigned u; float f; } v; v.u = ((unsigned)s) << 16; return v.f; }
DEV float sigm(float x) { return 1.f / (1.f + __expf(-x)); }
DEV float tanhfast(float x) { float e = __expf(2.f * x); return (e - 1.f) / (e + 1.f); }

#define MFMA(a,b,c) __builtin_amdgcn_mfma_f32_16x16x32_bf16((a),(b),(c),0,0,0)

// ---- coherent (L1+L2 bypass) memory ops: sc0 sc1 ----
DEV void st_coh_f32(float* p, float v) {
  asm volatile("global_store_dword %0, %1, off sc0 sc1" :: "v"(p), "v"(v) : "memory");
}
DEV void st_coh_b16(u16* p, u16 v) {
  unsigned vv = v;
  asm volatile("global_store_short %0, %1, off sc0 sc1" :: "v"(p), "v"(vv) : "memory");
}
DEV float ld_coh_f32(const float* p) {
  float v;
  asm volatile("global_load_dword %0, %1, off sc0 sc1\n\t"
               "s_waitcnt vmcnt(0)" : "=&v"(v) : "v"(p) : "memory");
  return v;
}
// four 16B coherent loads at +0/+64/+128/+192 bytes, one waitcnt
DEV void ld4_coh(const u16* p, short8& a0, short8& a1, short8& a2, short8& a3) {
  asm volatile(
    "global_load_dwordx4 %0, %4, off sc0 sc1\n\t"
    "global_load_dwordx4 %1, %4, off offset:64 sc0 sc1\n\t"
    "global_load_dwordx4 %2, %4, off offset:128 sc0 sc1\n\t"
    "global_load_dwordx4 %3, %4, off offset:192 sc0 sc1\n\t"
    "s_waitcnt vmcnt(0)"
    : "=&v"(a0), "=&v"(a1), "=&v"(a2), "=&v"(a3)
    : "v"(p) : "memory");
}
DEV void ld4p_coh_f32x4(const float* p0, const float* p1, const float* p2, const float* p3,
                        f32x4& d0, f32x4& d1, f32x4& d2, f32x4& d3) {
  asm volatile(
    "global_load_dwordx4 %0, %4, off sc0 sc1\n\t"
    "global_load_dwordx4 %1, %5, off sc0 sc1\n\t"
    "global_load_dwordx4 %2, %6, off sc0 sc1\n\t"
    "global_load_dwordx4 %3, %7, off sc0 sc1\n\t"
    "s_waitcnt vmcnt(0)"
    : "=&v"(d0), "=&v"(d1), "=&v"(d2), "=&v"(d3)
    : "v"(p0), "v"(p1), "v"(p2), "v"(p3) : "memory");
}

// relaxed grid barrier: no fences, no L2 flush. Data visibility is provided
// by sc01 stores (at coherent point) drained by vmcnt(0) before arrival.
DEV void gbar(unsigned* cnt, unsigned ep) {
  asm volatile("s_waitcnt vmcnt(0)" ::: "memory");
  __syncthreads();
  if (threadIdx.x == 0)
    __hip_atomic_fetch_add(&cnt[blockIdx.x & 15u], 1u, __ATOMIC_RELAXED, __HIP_MEMORY_SCOPE_AGENT);
  if (threadIdx.x < 16) {
    unsigned tgt = ep * (NBLK / 16u);
    while (__hip_atomic_load(&cnt[threadIdx.x], __ATOMIC_RELAXED, __HIP_MEMORY_SCOPE_AGENT) < tgt)
      __builtin_amdgcn_s_sleep(2);
  }
  __syncthreads();
}

__global__ __launch_bounds__(TPB) void attn_rnn_kernel(Args A) {
  const int tid  = (int)threadIdx.x;
  const int lane = tid & 63;
  const int lwv  = tid >> 6;
  const int swv  = lwv * NBLK + (int)blockIdx.x;
  const int gtid = (int)blockIdx.x * TPB + tid;
  const int NT   = NBLK * TPB;
  const int l15  = lane & 15;
  const int koff = (lane >> 4) * 8;
  const int row4 = (lane >> 4) * 4;
  const int myb  = (int)blockIdx.x >> 2;   // batch owned by this block
  const int mydq = (int)blockIdx.x & 3;    // d-quarter owned
  extern __shared__ char smem[];
  u16*   encL   = (u16*)smem;               // [512][128] bf16, 128KB
  float* pbuf   = (float*)(smem + 131072);  // [512]
  float* part   = pbuf + 512;               // [8][128]
  float* redbuf = part + 1024;              // [16]
  unsigned ep = 0;

  // ---------------- P0: conversions (sc01 stores) / LDS enc / gather ----------------
  for (int i = tid; i < 512 * 128; i += TPB) {
    int l = i >> 7, dd = i & 127;
    encL[i] = f2bf(A.enc[((myb * 512) + l) * 512 + mydq * 128 + dd]);
  }
  for (int i = gtid; i < 512 * 256; i += NT) { int l = i >> 8, k = i & 255; st_coh_b16(A.Wax + i, f2bf(A.Wattn[l * 768 + k])); }
  for (int i = gtid; i < 512 * 512; i += NT) { int l = i >> 9, d = i & 511; st_coh_b16(A.Wah + i, f2bf(A.Wattn[l * 768 + 256 + d])); }
  for (int i = gtid; i < 512 * 256; i += NT) { int l = i >> 8, k = i & 255; st_coh_b16(A.Wcx + i, f2bf(A.Wcomb[l * 768 + k])); }
  for (int i = gtid; i < 512 * 512; i += NT) { int l = i >> 9, d = i & 511; st_coh_b16(A.Wcc + i, f2bf(A.Wcomb[l * 768 + 256 + d])); }
  for (int i = gtid; i < 2048 * 1024; i += NT) { int n = i >> 10, k = i & 1023;
    st_coh_b16(A.Wg + i, f2bf(k < 512 ? A.Wih[n * 512 + k] : A.Whh[n * 512 + (k - 512)])); }
  for (int i = gtid; i < 256 * 512; i += NT) st_coh_b16(A.WoutB + i, f2bf(A.Wout[i]));
  for (int i = gtid; i < 1008 * 256; i += NT) { int v = i >> 8; st_coh_b16(A.commB + i, (v < 1000) ? f2bf(A.common[i]) : (u16)0); }
  for (int i = gtid; i < 64 * 112 * 256; i += NT) { int b = i / (112 * 256); int r = i - b * (112 * 256);
    int v = r >> 8; int k = r & 255; st_coh_b16(A.obeB + i, (v < 100) ? f2bf(A.obe[(b * 100 + v) * 256 + k]) : (u16)0); }
  for (int i = gtid; i < 2048; i += NT) st_coh_f32(A.bg + i, A.bih[i] + A.bhh[i]);
  for (int i = gtid; i < 64 * 512; i += NT) { st_coh_f32(A.cst + i, 0.f); st_coh_b16(A.h0 + i, 0); st_coh_b16(A.h1 + i, 0); }
  // embedding gather -> xbf[(t*64+b)][256]
  for (int task = swv; task < TS * 64; task += NWAVE) {
    int t = task >> 6, b = task & 63;
    int idx = A.tidx[b * 128 + t];
    const float* src = (idx < 1000) ? (A.common + idx * 256) : (A.obe + (b * 100 + (idx - 1000)) * 256);
    for (int j = 0; j < 4; ++j) { int k = j * 64 + lane; st_coh_b16(A.xbf + (t * 64 + b) * 256 + k, f2bf(src[k])); }
  }
  gbar(A.bar, ++ep);

  // ---------------- P1: ax = x@Wax^T + battn ; cx = x@Wcx^T + bcomb ----------------
  for (int task = swv; task < 2 * 508 * 32; task += NWAVE) {
    int which = (task >= 508 * 32) ? 1 : 0;
    int tk = task - which * (508 * 32);
    int mt = tk >> 5, nt = tk & 31;
    const u16* Wp = which ? A.Wcx : A.Wax;
    const u16* Ap = A.xbf + (mt * 16 + l15) * 256 + koff;
    const u16* Bp = Wp + (nt * 16 + l15) * 256 + koff;
    f32x4 acc = {0.f, 0.f, 0.f, 0.f};
    for (int k0 = 0; k0 < 256; k0 += 32)
      acc = MFMA(*(const short8*)(Ap + k0), *(const short8*)(Bp + k0), acc);
    const float* bias = which ? A.bcomb : A.battn;
    u16* dst = which ? A.cx : A.ax;
    for (int r = 0; r < 4; ++r) {
      int m = mt * 16 + row4 + r, n = nt * 16 + l15;
      st_coh_b16(dst + m * 512 + n, f2bf(acc[r] + bias[n]));
    }
  }
  gbar(A.bar, ++ep);

  // ---------------- main recurrence ----------------
  for (int t = 0; t < TS; ++t) {
    const u16* hcur = (t & 1) ? A.h1 : A.h0;
    u16* hnxt = (t & 1) ? A.h0 : A.h1;

    // Phase A: aw = h@Wah^T + ax[t] (128 tiles) AND gh = h@Whh^T (512 tiles)
    if (swv < 640) {
      const bool isAw = (swv < 128);
      const int rem = isAw ? swv : ((swv - 128) & 127);
      const int g   = isAw ? 0 : ((swv - 128) >> 7);
      const int mt = rem >> 5, nt = rem & 31;
      const int am = mt * 16 + l15;
      const u16* hrow = hcur + am * 512 + koff;
      short8 ha[16];
      #pragma unroll
      for (int q = 0; q < 4; ++q)
        ld4_coh(hrow + q * 128, ha[4*q+0], ha[4*q+1], ha[4*q+2], ha[4*q+3]);
      const u16* Bp = isAw ? (A.Wah + (nt * 16 + l15) * 512 + koff)
                           : (A.Wg + (g * 512 + nt * 16 + l15) * 1024 + 512 + koff);
      f32x4 acc = {0.f, 0.f, 0.f, 0.f};
      #pragma unroll
      for (int kk = 0; kk < 16; ++kk)
        acc = MFMA(ha[kk], *(const short8*)(Bp + kk * 32), acc);
      if (isAw) {
        #pragma unroll
        for (int r = 0; r < 4; ++r) {
          int m = mt * 16 + row4 + r, n = nt * 16 + l15;
          st_coh_f32(A.aw + m * 512 + n, acc[r] + bf2f(A.ax[(t * 64 + m) * 512 + n]));
        }
      } else {
        #pragma unroll
        for (int r = 0; r < 4; ++r) {
          int m = mt * 16 + row4 + r, u = nt * 16 + l15;
          st_coh_f32(A.gh + m * 2048 + u * 4 + g, acc[r]);
        }
      }
    }
    gbar(A.bar, ++ep);

    // Phase B: per-block softmax(aw[myb]) + ctx from LDS enc slice
    {
      float a0 = ld_coh_f32(A.aw + myb * 512 + tid);
      float mx = a0;
      for (int off = 1; off < 64; off <<= 1) mx = fmaxf(mx, __shfl_xor(mx, off));
      if (lane == 0) redbuf[lwv] = mx;
      __syncthreads();
      mx = redbuf[0];
      for (int k = 1; k < 8; ++k) mx = fmaxf(mx, redbuf[k]);
      float e = __expf(a0 - mx);
      pbuf[tid] = e;
      float s = e;
      for (int off = 1; off < 64; off <<= 1) s += __shfl_xor(s, off);
      if (lane == 0) redbuf[8 + lwv] = s;
      __syncthreads();
      s = 0.f;
      for (int k = 0; k < 8; ++k) s += redbuf[8 + k];
      float inv = 1.f / s;
      int dd2 = tid & 63, lh = tid >> 6;
      float c0 = 0.f, c1 = 0.f;
      const u16* eb = encL + dd2 * 2;
      const float* pb = pbuf + lh * 64;
      for (int j = 0; j < 64; ++j) {
        unsigned ev = *(const unsigned*)(eb + (lh * 64 + j) * 128);
        float p = pb[j];
        c0 += p * bf2f((u16)(ev & 0xffffu));
        c1 += p * bf2f((u16)(ev >> 16));
      }
      *(float2*)(part + lh * 128 + dd2 * 2) = make_float2(c0, c1);
      __syncthreads();
      if (tid < 128) {
        float cs = 0.f;
        for (int k = 0; k < 8; ++k) cs += part[k * 128 + tid];
        st_coh_b16(A.ctxbf + myb * 512 + mydq * 128 + tid, f2bf(cs * inv));
      }
    }
    gbar(A.bar, ++ep);

    // Phase C: r = relu(ctx @ Wcc^T + cx[t])
    if (swv < 128) {
      int mt = swv >> 5, nt = swv & 31;
      int am = mt * 16 + l15;
      const u16* crow = A.ctxbf + am * 512 + koff;
      short8 ca[16];
      #pragma unroll
      for (int q = 0; q < 4; ++q)
        ld4_coh(crow + q * 128, ca[4*q+0], ca[4*q+1], ca[4*q+2], ca[4*q+3]);
      const u16* Bp = A.Wcc + (nt * 16 + l15) * 512 + koff;
      f32x4 acc = {0.f, 0.f, 0.f, 0.f};
      #pragma unroll
      for (int kk = 0; kk < 16; ++kk)
        acc = MFMA(ca[kk], *(const short8*)(Bp + kk * 32), acc);
      #pragma unroll
      for (int r = 0; r < 4; ++r) {
        int m = mt * 16 + row4 + r, n = nt * 16 + l15;
        st_coh_b16(A.rbf + m * 512 + n, f2bf(fmaxf(acc[r] + bf2f(A.cx[(t * 64 + m) * 512 + n]), 0.f)));
      }
    }
    gbar(A.bar, ++ep);

    // Phase D: gates = r@Wih^T + gh + bg ; cell update (4 gate tiles per wave)
    if (swv < 128) {
      int mt = swv >> 5, ut = swv & 31;
      int am = mt * 16 + l15, nr = ut * 16 + l15;
      const u16* rrow = A.rbf + am * 512 + koff;
      short8 ra[16];
      #pragma unroll
      for (int q = 0; q < 4; ++q)
        ld4_coh(rrow + q * 128, ra[4*q+0], ra[4*q+1], ra[4*q+2], ra[4*q+3]);
      f32x4 ai = {0.f,0.f,0.f,0.f}, af = ai, ag = ai, ao = ai;
      #pragma unroll
      for (int kk = 0; kk < 16; ++kk) {
        int k0 = kk * 32;
        short8 a = ra[kk];
        short8 b0 = *(const short8*)(A.Wg + (nr) * 1024 + k0 + koff);
        short8 b1 = *(const short8*)(A.Wg + (512 + nr) * 1024 + k0 + koff);
        short8 b2 = *(const short8*)(A.Wg + (1024 + nr) * 1024 + k0 + koff);
        short8 b3 = *(const short8*)(A.Wg + (1536 + nr) * 1024 + k0 + koff);
        ai = MFMA(a, b0, ai); af = MFMA(a, b1, af); ag = MFMA(a, b2, ag); ao = MFMA(a, b3, ao);
      }
      int ucol = ut * 16 + l15;
      const float* gb = A.gh + ucol * 4;
      f32x4 g0, g1, g2, g3;
      ld4p_coh_f32x4(gb + (mt*16+row4+0)*2048, gb + (mt*16+row4+1)*2048,
                     gb + (mt*16+row4+2)*2048, gb + (mt*16+row4+3)*2048, g0, g1, g2, g3);
      #pragma unroll
      for (int r = 0; r < 4; ++r) {
        f32x4 gv = (r == 0) ? g0 : (r == 1) ? g1 : (r == 2) ? g2 : g3;
        int m = mt * 16 + row4 + r, u = ucol;
        float gi = ai[r] + gv[0] + A.bg[u];
        float gf = af[r] + gv[1] + A.bg[512 + u];
        float gg = ag[r] + gv[2] + A.bg[1024 + u];
        float go = ao[r] + gv[3] + A.bg[1536 + u];
        float cn = sigm(gf) * A.cst[m * 512 + u] + sigm(gi) * tanhfast(gg);
        float hn = sigm(go) * tanhfast(cn);
        A.cst[m * 512 + u] = cn;          // block-local (same wave every step)
        u16 hb = f2bf(hn);
        st_coh_b16(hnxt + m * 512 + u, hb);
        st_coh_b16(A.hh + (t * 64 + m) * 512 + u, hb);
      }
    }
    gbar(A.bar, ++ep);
  }

  // ---------------- P2: out = hh @ Wout^T + bout   (M=8128) ----------------
  for (int task = swv; task < 508 * 16; task += NWAVE) {
    int mt = task >> 4, nt = task & 15;
    const u16* Ap = A.hh + (mt * 16 + l15) * 512 + koff;     // first normal touch: fresh
    const u16* Bp = A.WoutB + (nt * 16 + l15) * 512 + koff;
    f32x4 acc = {0.f,0.f,0.f,0.f};
    for (int k0 = 0; k0 < 512; k0 += 32)
      acc = MFMA(*(const short8*)(Ap + k0), *(const short8*)(Bp + k0), acc);
    for (int r = 0; r < 4; ++r) {
      int m = mt * 16 + row4 + r, n = nt * 16 + l15;
      st_coh_b16(A.outbf + m * 256 + n, f2bf(acc[r] + A.bout[n]));
    }
  }
  gbar(A.bar, ++ep);

  // ---------------- P3: proj_common + proj_batched -> d_out ----------------
  for (int task = swv; task < 508 * 63; task += NWAVE) {
    int mt = task / 63, nt = task - mt * 63;
    const u16* Ap = A.outbf + (mt * 16 + l15) * 256 + koff;
    const u16* Bp = A.commB + (nt * 16 + l15) * 256 + koff;
    f32x4 acc = {0.f,0.f,0.f,0.f};
    for (int k0 = 0; k0 < 256; k0 += 32)
      acc = MFMA(*(const short8*)(Ap + k0), *(const short8*)(Bp + k0), acc);
    for (int r = 0; r < 4; ++r) {
      int m = mt * 16 + row4 + r, n = nt * 16 + l15;
      if (n < 1000) { int tt = m >> 6, b = m & 63; st_coh_f32(A.out + ((b * 127) + tt) * 1100 + n, acc[r]); }
    }
  }
  for (int task = swv; task < 64 * 56; task += NWAVE) {
    int b = task / 56, r2 = task - b * 56;
    int mt = r2 / 7, nt = r2 - mt * 7;
    int am = mt * 16 + l15;
    const u16* Bp = A.obeB + (b * 112 + nt * 16 + l15) * 256 + koff;
    f32x4 acc = {0.f,0.f,0.f,0.f};
    short8 z8 = {0,0,0,0,0,0,0,0};
    for (int k0 = 0; k0 < 256; k0 += 32) {
      short8 a = (am < 127) ? *(const short8*)(A.outbf + (am * 64 + b) * 256 + k0 + koff) : z8;
      short8 b8 = *(const short8*)(Bp + k0);
      acc = MFMA(a, b8, acc);
    }
    for (int r = 0; r < 4; ++r) {
      int tt = mt * 16 + row4 + r, v = nt * 16 + l15;
      if (tt < 127 && v < 100) st_coh_f32(A.out + ((b * 127) + tt) * 1100 + 1000 + v, acc[r]);
    }
  }
  gbar(A.bar, ++ep);

  // ---------------- P4: log-softmax in place, wave per (t,b) row ----------------
  for (int task = swv; task < TS * 64; task += NWAVE) {
    int t = task >> 6, b = task & 63;
    float* ptr = A.out + ((b * 127) + t) * 1100;   // first normal touch of these lines
    float v[18]; float mx = -1e30f;
    for (int j = 0; j < 18; ++j) { int i = j * 64 + lane; v[j] = (i < 1100) ? ptr[i] : -1e30f; mx = fmaxf(mx, v[j]); }
    for (int off = 1; off < 64; off <<= 1) mx = fmaxf(mx, __shfl_xor(mx, off));
    float s = 0.f;
    for (int j = 0; j < 18; ++j) { int i = j * 64 + lane; if (i < 1100) s += __expf(v[j] - mx); }
    for (int off = 1; off < 64; off <<= 1) s += __shfl_xor(s, off);
    float lz = mx + __logf(s);
    for (int j = 0; j < 18; ++j) { int i = j * 64 + lane; if (i < 1100) ptr[i] = v[j] - lz; }
  }
}

extern "C" void kernel_launch(void* const* d_in, const int* in_sizes, int n_in,
                              void* d_out, int out_size, void* d_ws, size_t ws_size,
                              hipStream_t stream) {
  (void)in_sizes; (void)n_in; (void)out_size; (void)ws_size;
  char* ws = (char*)d_ws;
  size_t off = 0;
  auto alloc = [&](size_t bytes) -> void* {
    void* p = (void*)(ws + off);
    off = (off + bytes + 255) & ~((size_t)255);
    return p;
  };
  Args A;
  A.enc    = (const float*)d_in[0];
  A.obe    = (const float*)d_in[2];
  A.tidx   = (const int*)d_in[4];
  A.common = (const float*)d_in[5];
  A.Wattn  = (const float*)d_in[6];
  A.battn  = (const float*)d_in[7];
  A.Wcomb  = (const float*)d_in[8];
  A.bcomb  = (const float*)d_in[9];
  A.Wih    = (const float*)d_in[10];
  A.bih    = (const float*)d_in[11];
  A.Whh    = (const float*)d_in[12];
  A.bhh    = (const float*)d_in[13];
  A.Wout   = (const float*)d_in[14];
  A.bout   = (const float*)d_in[15];
  A.out    = (float*)d_out;
  A.bar    = (unsigned*)alloc(256);
  A.ax     = (u16*)alloc((size_t)TS * 64 * 512 * 2);
  A.cx     = (u16*)alloc((size_t)TS * 64 * 512 * 2);
  A.xbf    = (u16*)alloc((size_t)TS * 64 * 256 * 2);
  A.Wax    = (u16*)alloc((size_t)512 * 256 * 2);
  A.Wah    = (u16*)alloc((size_t)512 * 512 * 2);
  A.Wcx    = (u16*)alloc((size_t)512 * 256 * 2);
  A.Wcc    = (u16*)alloc((size_t)512 * 512 * 2);
  A.Wg     = (u16*)alloc((size_t)2048 * 1024 * 2);
  A.WoutB  = (u16*)alloc((size_t)256 * 512 * 2);
  A.commB  = (u16*)alloc((size_t)1008 * 256 * 2);
  A.obeB   = (u16*)alloc((size_t)64 * 112 * 256 * 2);
  A.bg     = (float*)alloc((size_t)2048 * 4);
  A.aw     = (float*)alloc((size_t)64 * 512 * 4);
  A.gh     = (float*)alloc((size_t)64 * 2048 * 4);
  A.cst    = (float*)alloc((size_t)64 * 512 * 4);
  A.rbf    = (u16*)alloc((size_t)64 * 512 * 2);
  A.h0     = (u16*)alloc((size_t)64 * 512 * 2);
  A.h1     = (u16*)alloc((size_t)64 * 512 * 2);
  A.ctxbf  = (u16*)alloc((size_t)64 * 512 * 2);
  A.hh     = (u16*)alloc((size_t)TS * 64 * 512 * 2);
  A.outbf  = (u16*)alloc((size_t)TS * 64 * 256 * 2);
  hipFuncSetAttribute((const void*)attn_rnn_kernel,
                      hipFuncAttributeMaxDynamicSharedMemorySize, SMEM_BYTES);
  hipMemsetAsync(A.bar, 0, 256, stream);
  hipLaunchKernelGGL(attn_rnn_kernel, dim3(NBLK), dim3(TPB), SMEM_BYTES, stream, A);
}